// Round 1
// baseline (909.264 us; speedup 1.0000x reference)
//
#include <hip/hip_runtime.h>
#include <cfloat>

#define BATCH 4
#define KQ    2048   // queries per batch
#define NP    4096   // points per batch
#define CIN   64
#define CMID  32
#define NB    16     // neighbors

// ---------------------------------------------------------------------------
// Kernel 1: per query (b,k): distances -> top-16 -> edge MLP -> e row (2048)
// One block (256 threads) per query. Writes E[8192][2048].
// ---------------------------------------------------------------------------
__global__ __launch_bounds__(256) void topk_edge_e(
    const float* __restrict__ keys, const float* __restrict__ points,
    const float* __restrict__ feats,
    const float* __restrict__ wc0_W, const float* __restrict__ wc0_b,
    const float* __restrict__ wc1_W, const float* __restrict__ wc1_b,
    const float* __restrict__ wc2_W, const float* __restrict__ wc2_b,
    float* __restrict__ E) {
  __shared__ float sdist[NP];          // 16 KB
  __shared__ float red_d[256];
  __shared__ int   red_i[256];
  __shared__ int   nidx[NB];
  __shared__ float m_lds[NB][CMID + 1];
  __shared__ float f_lds[NB][CIN];
  __shared__ float w0[96], b0v[32], w1[1024], b1v[32], w2[1024], b2v[32];

  const int tid = threadIdx.x;
  const int b   = blockIdx.x >> 11;    // / KQ

  // stage tiny MLP weights into LDS
  if (tid < 96) w0[tid] = wc0_W[tid];
  for (int i = tid; i < 1024; i += 256) { w1[i] = wc1_W[i]; w2[i] = wc2_W[i]; }
  if (tid < 32) { b0v[tid] = wc0_b[tid]; b1v[tid] = wc1_b[tid]; b2v[tid] = wc2_b[tid]; }

  const float kx = keys[blockIdx.x * 3 + 0];
  const float ky = keys[blockIdx.x * 3 + 1];
  const float kz = keys[blockIdx.x * 3 + 2];

  for (int i = tid; i < NP; i += 256) {
    const float* p = points + ((size_t)b * NP + i) * 3;
    float dx = p[0] - kx, dy = p[1] - ky, dz = p[2] - kz;
    sdist[i] = dx * dx + dy * dy + dz * dz;
  }
  __syncthreads();

  // 16 x argmin selection (tie -> lower index, matching lax.top_k stability)
  for (int s = 0; s < NB; ++s) {
    float bd = FLT_MAX; int bi = NP;
    for (int i = tid; i < NP; i += 256) {
      float d = sdist[i];
      if (d < bd) { bd = d; bi = i; }   // strict < keeps lowest index in-thread
    }
    red_d[tid] = bd; red_i[tid] = bi;
    __syncthreads();
    for (int off = 128; off > 0; off >>= 1) {
      if (tid < off) {
        float d2 = red_d[tid + off]; int i2 = red_i[tid + off];
        float d1 = red_d[tid];       int i1 = red_i[tid];
        if (d2 < d1 || (d2 == d1 && i2 < i1)) { red_d[tid] = d2; red_i[tid] = i2; }
      }
      __syncthreads();
    }
    if (tid == 0) { nidx[s] = red_i[0]; sdist[red_i[0]] = FLT_MAX; }
    __syncthreads();
  }

  // gather neighbor features [16][64]
  for (int j = tid; j < NB * CIN; j += 256) {
    int n = j >> 6, c = j & 63;
    f_lds[n][c] = feats[((size_t)b * NP + nidx[n]) * CIN + c];
  }

  // edge MLP: threads 0..15 each run one edge's 3->32->32->32 MLP
  if (tid < NB) {
    const int idx = nidx[tid];
    const float* p = points + ((size_t)b * NP + idx) * 3;
    const float rx = p[0] - kx, ry = p[1] - ky, rz = p[2] - kz;
    float h1[32], h2[32];
#pragma unroll
    for (int o = 0; o < 32; ++o)
      h1[o] = fmaxf(0.f, rx * w0[o] + ry * w0[32 + o] + rz * w0[64 + o] + b0v[o]);
#pragma unroll
    for (int o = 0; o < 32; ++o) {
      float a = b1v[o];
#pragma unroll
      for (int i = 0; i < 32; ++i) a += h1[i] * w1[i * 32 + o];
      h2[o] = fmaxf(0.f, a);
    }
#pragma unroll
    for (int o = 0; o < 32; ++o) {
      float a = b2v[o];
#pragma unroll
      for (int i = 0; i < 32; ++i) a += h2[i] * w2[i * 32 + o];
      m_lds[tid][o] = a;
    }
  }
  __syncthreads();

  // e[mid*64 + c] = sum_n m[n][mid] * f[n][c]
  float* Erow = E + (size_t)blockIdx.x * 2048;
  for (int j = tid; j < 2048; j += 256) {
    int mid = j >> 6, c = j & 63;
    float a = 0.f;
#pragma unroll
    for (int n = 0; n < NB; ++n) a += m_lds[n][mid] * f_lds[n][c];
    Erow[j] = a;
  }
}

// ---------------------------------------------------------------------------
// Kernel 2/3: fp32 tiled GEMM  C = act(A[M,K] @ W[K,N] + bias)
// 64x64 tile per 256-thread block, 4x4 per thread, K-tiles of 32.
// ---------------------------------------------------------------------------
template <bool RELU>
__global__ __launch_bounds__(256) void gemm_bias(
    const float* __restrict__ A, const float* __restrict__ W,
    const float* __restrict__ bias, float* __restrict__ C,
    int M, int K, int N) {
  // stride 68 floats = 272 B: keeps float4 rows 16B-aligned, breaks pow2 banks
  __shared__ __align__(16) float a_t[32][68];  // [kk][r]
  __shared__ __align__(16) float b_t[32][68];  // [kk][c]
  const int tid = threadIdx.x;
  const int m0 = blockIdx.x * 64;
  const int n0 = blockIdx.y * 64;
  const int tr = tid >> 4, tc = tid & 15;
  const int r0 = tr * 4, c0 = tc * 4;

  float acc[4][4] = {};

  for (int k0 = 0; k0 < K; k0 += 32) {
#pragma unroll
    for (int t = 0; t < 8; ++t) {
      int j = tid + t * 256;
      int r = j >> 5, kk = j & 31;           // A tile: 64 rows x 32 k
      a_t[kk][r] = A[(size_t)(m0 + r) * K + (k0 + kk)];
      int kk2 = j >> 6, c = j & 63;          // B tile: 32 k x 64 cols
      b_t[kk2][c] = W[(size_t)(k0 + kk2) * N + (n0 + c)];
    }
    __syncthreads();
#pragma unroll
    for (int kk = 0; kk < 32; ++kk) {
      float4 av = *reinterpret_cast<const float4*>(&a_t[kk][r0]);
      float4 bv = *reinterpret_cast<const float4*>(&b_t[kk][c0]);
      float ar[4] = {av.x, av.y, av.z, av.w};
      float br[4] = {bv.x, bv.y, bv.z, bv.w};
#pragma unroll
      for (int i = 0; i < 4; ++i)
#pragma unroll
        for (int j = 0; j < 4; ++j) acc[i][j] += ar[i] * br[j];
    }
    __syncthreads();
  }

#pragma unroll
  for (int i = 0; i < 4; ++i) {
    float4 o;
#pragma unroll
    for (int j = 0; j < 4; ++j) {
      float v = acc[i][j] + bias[n0 + c0 + j];
      if (RELU) v = fmaxf(v, 0.f);
      (&o.x)[j] = v;
    }
    *reinterpret_cast<float4*>(&C[(size_t)(m0 + r0 + i) * N + (n0 + c0)]) = o;
  }
}

// ---------------------------------------------------------------------------
extern "C" void kernel_launch(void* const* d_in, const int* in_sizes, int n_in,
                              void* d_out, int out_size, void* d_ws, size_t ws_size,
                              hipStream_t stream) {
  const float* keys   = (const float*)d_in[0];
  const float* points = (const float*)d_in[1];
  const float* feats  = (const float*)d_in[2];
  const float* wc0_W  = (const float*)d_in[3];
  const float* wc0_b  = (const float*)d_in[4];
  const float* wc1_W  = (const float*)d_in[5];
  const float* wc1_b  = (const float*)d_in[6];
  const float* wc2_W  = (const float*)d_in[7];
  const float* wc2_b  = (const float*)d_in[8];
  const float* fc0_W  = (const float*)d_in[9];
  const float* fc0_b  = (const float*)d_in[10];
  const float* fc1_W  = (const float*)d_in[11];
  const float* fc1_b  = (const float*)d_in[12];
  float* out = (float*)d_out;

  const int M = BATCH * KQ;                 // 8192 rows
  float* E = (float*)d_ws;                  // 8192*2048 f32 = 64 MB
  float* H = E + (size_t)M * 2048;          // 8192*256  f32 =  8 MB

  topk_edge_e<<<M, 256, 0, stream>>>(keys, points, feats,
                                     wc0_W, wc0_b, wc1_W, wc1_b, wc2_W, wc2_b, E);
  gemm_bias<true><<<dim3(M / 64, 256 / 64), 256, 0, stream>>>(E, fc0_W, fc0_b, H,
                                                              M, 2048, 256);
  gemm_bias<false><<<dim3(M / 64, 128 / 64), 256, 0, stream>>>(H, fc1_W, fc1_b, out,
                                                               M, 256, 128);
}

// Round 2
// 466.152 us; speedup vs baseline: 1.9506x; 1.9506x over previous
//
#include <hip/hip_runtime.h>
#include <cfloat>
#include <climits>

#define BATCH 4
#define KQ    2048   // queries per batch
#define NP    4096   // points per batch
#define CIN   64
#define CMID  32
#define NB    16     // neighbors
#define PPT   16     // points per thread (NP/256)
#define NBINS 512
#define CANDCAP 1024

// ---------------------------------------------------------------------------
// Kernel 1: per query (b,k): distances -> radix-select top-16 -> edge MLP ->
// e row (2048). One block (256 threads) per query. Writes E[8192][2048].
//
// Selection uses the monotonicity of IEEE bits for non-negative floats:
// bucket = bits >> 22 (exp + 1 mantissa bit). Histogram once, find threshold
// bin, collect. Only the SET of 16 neighbors matters (einsum sums over n),
// so no ordering is needed; ties at the boundary break by lower index to
// match lax.top_k set membership.
// ---------------------------------------------------------------------------
__global__ __launch_bounds__(256) void topk_edge_e(
    const float* __restrict__ keys, const float* __restrict__ points,
    const float* __restrict__ feats,
    const float* __restrict__ wc0_W, const float* __restrict__ wc0_b,
    const float* __restrict__ wc1_W, const float* __restrict__ wc1_b,
    const float* __restrict__ wc2_W, const float* __restrict__ wc2_b,
    float* __restrict__ E) {
  __shared__ int   hist[NBINS];            // 2 KB
  __shared__ float cand_d[CANDCAP];        // 4 KB
  __shared__ int   cand_i[CANDCAP];        // 4 KB
  __shared__ int   nidx[NB];
  __shared__ int   sel_cnt, cand_cnt, sBin, sCbelow;
  __shared__ float m_lds[NB][CMID + 1];
  __shared__ float f_lds[NB][CIN];
  __shared__ float w0[96], b0v[32], w1[1024], b1v[32], w2[1024], b2v[32];

  const int tid = threadIdx.x;
  const int b   = blockIdx.x >> 11;        // / KQ

  // stage tiny MLP weights into LDS; zero histogram & counters
  if (tid < 96) w0[tid] = wc0_W[tid];
  for (int i = tid; i < 1024; i += 256) { w1[i] = wc1_W[i]; w2[i] = wc2_W[i]; }
  if (tid < 32) { b0v[tid] = wc0_b[tid]; b1v[tid] = wc1_b[tid]; b2v[tid] = wc2_b[tid]; }
  for (int i = tid; i < NBINS; i += 256) hist[i] = 0;
  if (tid == 0) { sel_cnt = 0; cand_cnt = 0; }

  const float kx = keys[blockIdx.x * 3 + 0];
  const float ky = keys[blockIdx.x * 3 + 1];
  const float kz = keys[blockIdx.x * 3 + 2];
  __syncthreads();

  // pass 1: distances into registers + bucket histogram
  float dreg[PPT];
#pragma unroll
  for (int t = 0; t < PPT; ++t) {
    const int i = tid + t * 256;
    const float* p = points + ((size_t)b * NP + i) * 3;
    float dx = p[0] - kx, dy = p[1] - ky, dz = p[2] - kz;
    float d = dx * dx + dy * dy + dz * dz;
    dreg[t] = d;
    atomicAdd(&hist[__float_as_uint(d) >> 22], 1);
  }
  __syncthreads();

  // wave 0: find threshold bin (first bin where cumulative count >= 16)
  if (tid < 64) {
    const int base = tid * 8;
    int c[8]; int s = 0;
#pragma unroll
    for (int j = 0; j < 8; ++j) { c[j] = hist[base + j]; s += c[j]; }
    int incl = s;
#pragma unroll
    for (int off = 1; off < 64; off <<= 1) {
      int u = __shfl_up(incl, off);
      if (tid >= off) incl += u;
    }
    unsigned long long bal = __ballot(incl >= NB);
    int firstlane = __ffsll((long long)bal) - 1;
    if (tid == firstlane) {
      int cum = incl - s;
      int B = base;
#pragma unroll
      for (int j = 0; j < 8; ++j) {
        if (cum + c[j] >= NB) { B = base + j; break; }
        cum += c[j];
      }
      sBin = B; sCbelow = cum;
    }
  }
  __syncthreads();

  const unsigned B = (unsigned)sBin;

  // pass 2: collect. bucket < B -> selected outright; == B -> candidate.
#pragma unroll
  for (int t = 0; t < PPT; ++t) {
    const int i = tid + t * 256;
    const unsigned bk = __float_as_uint(dreg[t]) >> 22;
    if (bk < B) {
      int pos = atomicAdd(&sel_cnt, 1);
      nidx[pos] = i;                        // pos < 16 guaranteed (Cbelow < 16)
    } else if (bk == B) {
      int pos = atomicAdd(&cand_cnt, 1);
      if (pos < CANDCAP) { cand_d[pos] = dreg[t]; cand_i[pos] = i; }
    }
  }
  __syncthreads();

  // wave 0: pick remaining = 16 - Cbelow smallest among candidates (tie: low idx)
  if (tid < 64) {
    const int rem = NB - sCbelow;
    const int cc  = min(cand_cnt, CANDCAP);
    for (int s = 0; s < rem; ++s) {
      float bd = FLT_MAX; int bi = INT_MAX; int bp = -1;
      for (int j = tid; j < cc; j += 64) {
        float d = cand_d[j]; int ii = cand_i[j];
        if (d < bd || (d == bd && ii < bi)) { bd = d; bi = ii; bp = j; }
      }
#pragma unroll
      for (int off = 32; off > 0; off >>= 1) {
        float od = __shfl_down(bd, off);
        int   oi = __shfl_down(bi, off);
        int   op = __shfl_down(bp, off);
        if (od < bd || (od == bd && oi < bi)) { bd = od; bi = oi; bp = op; }
      }
      if (tid == 0) { nidx[sCbelow + s] = bi; cand_d[bp] = FLT_MAX; }
    }
  }
  __syncthreads();

  // gather neighbor features [16][64]
  for (int j = tid; j < NB * CIN; j += 256) {
    int n = j >> 6, c = j & 63;
    f_lds[n][c] = feats[((size_t)b * NP + nidx[n]) * CIN + c];
  }

  // edge MLP: threads 0..15 each run one edge's 3->32->32->32 MLP
  if (tid < NB) {
    const int idx = nidx[tid];
    const float* p = points + ((size_t)b * NP + idx) * 3;
    const float rx = p[0] - kx, ry = p[1] - ky, rz = p[2] - kz;
    float h1[32], h2[32];
#pragma unroll
    for (int o = 0; o < 32; ++o)
      h1[o] = fmaxf(0.f, rx * w0[o] + ry * w0[32 + o] + rz * w0[64 + o] + b0v[o]);
#pragma unroll
    for (int o = 0; o < 32; ++o) {
      float a = b1v[o];
#pragma unroll
      for (int i = 0; i < 32; ++i) a += h1[i] * w1[i * 32 + o];
      h2[o] = fmaxf(0.f, a);
    }
#pragma unroll
    for (int o = 0; o < 32; ++o) {
      float a = b2v[o];
#pragma unroll
      for (int i = 0; i < 32; ++i) a += h2[i] * w2[i * 32 + o];
      m_lds[tid][o] = a;
    }
  }
  __syncthreads();

  // e[mid*64 + c] = sum_n m[n][mid] * f[n][c]
  float* Erow = E + (size_t)blockIdx.x * 2048;
  for (int j = tid; j < 2048; j += 256) {
    int mid = j >> 6, c = j & 63;
    float a = 0.f;
#pragma unroll
    for (int n = 0; n < NB; ++n) a += m_lds[n][mid] * f_lds[n][c];
    Erow[j] = a;
  }
}

// ---------------------------------------------------------------------------
// Kernel 2/3: fp32 tiled GEMM  C = act(A[M,K] @ W[K,N] + bias)
// 64x64 tile per 256-thread block, 4x4 per thread, K-tiles of 32.
// ---------------------------------------------------------------------------
template <bool RELU>
__global__ __launch_bounds__(256) void gemm_bias(
    const float* __restrict__ A, const float* __restrict__ W,
    const float* __restrict__ bias, float* __restrict__ C,
    int M, int K, int N) {
  // stride 68 floats = 272 B: keeps float4 rows 16B-aligned, breaks pow2 banks
  __shared__ __align__(16) float a_t[32][68];  // [kk][r]
  __shared__ __align__(16) float b_t[32][68];  // [kk][c]
  const int tid = threadIdx.x;
  const int m0 = blockIdx.x * 64;
  const int n0 = blockIdx.y * 64;
  const int tr = tid >> 4, tc = tid & 15;
  const int r0 = tr * 4, c0 = tc * 4;

  float acc[4][4] = {};

  for (int k0 = 0; k0 < K; k0 += 32) {
#pragma unroll
    for (int t = 0; t < 8; ++t) {
      int j = tid + t * 256;
      int r = j >> 5, kk = j & 31;           // A tile: 64 rows x 32 k
      a_t[kk][r] = A[(size_t)(m0 + r) * K + (k0 + kk)];
      int kk2 = j >> 6, c = j & 63;          // B tile: 32 k x 64 cols
      b_t[kk2][c] = W[(size_t)(k0 + kk2) * N + (n0 + c)];
    }
    __syncthreads();
#pragma unroll
    for (int kk = 0; kk < 32; ++kk) {
      float4 av = *reinterpret_cast<const float4*>(&a_t[kk][r0]);
      float4 bv = *reinterpret_cast<const float4*>(&b_t[kk][c0]);
      float ar[4] = {av.x, av.y, av.z, av.w};
      float br[4] = {bv.x, bv.y, bv.z, bv.w};
#pragma unroll
      for (int i = 0; i < 4; ++i)
#pragma unroll
        for (int j = 0; j < 4; ++j) acc[i][j] += ar[i] * br[j];
    }
    __syncthreads();
  }

#pragma unroll
  for (int i = 0; i < 4; ++i) {
    float4 o;
#pragma unroll
    for (int j = 0; j < 4; ++j) {
      float v = acc[i][j] + bias[n0 + c0 + j];
      if (RELU) v = fmaxf(v, 0.f);
      (&o.x)[j] = v;
    }
    *reinterpret_cast<float4*>(&C[(size_t)(m0 + r0 + i) * N + (n0 + c0)]) = o;
  }
}

// ---------------------------------------------------------------------------
extern "C" void kernel_launch(void* const* d_in, const int* in_sizes, int n_in,
                              void* d_out, int out_size, void* d_ws, size_t ws_size,
                              hipStream_t stream) {
  const float* keys   = (const float*)d_in[0];
  const float* points = (const float*)d_in[1];
  const float* feats  = (const float*)d_in[2];
  const float* wc0_W  = (const float*)d_in[3];
  const float* wc0_b  = (const float*)d_in[4];
  const float* wc1_W  = (const float*)d_in[5];
  const float* wc1_b  = (const float*)d_in[6];
  const float* wc2_W  = (const float*)d_in[7];
  const float* wc2_b  = (const float*)d_in[8];
  const float* fc0_W  = (const float*)d_in[9];
  const float* fc0_b  = (const float*)d_in[10];
  const float* fc1_W  = (const float*)d_in[11];
  const float* fc1_b  = (const float*)d_in[12];
  float* out = (float*)d_out;

  const int M = BATCH * KQ;                 // 8192 rows
  float* E = (float*)d_ws;                  // 8192*2048 f32 = 64 MB
  float* H = E + (size_t)M * 2048;          // 8192*256  f32 =  8 MB

  topk_edge_e<<<M, 256, 0, stream>>>(keys, points, feats,
                                     wc0_W, wc0_b, wc1_W, wc1_b, wc2_W, wc2_b, E);
  gemm_bias<true><<<dim3(M / 64, 256 / 64), 256, 0, stream>>>(E, fc0_W, fc0_b, H,
                                                              M, 2048, 256);
  gemm_bias<false><<<dim3(M / 64, 128 / 64), 256, 0, stream>>>(H, fc1_W, fc1_b, out,
                                                               M, 256, 128);
}

// Round 3
// 243.178 us; speedup vs baseline: 3.7391x; 1.9169x over previous
//
#include <hip/hip_runtime.h>
#include <cfloat>
#include <climits>

#define BATCH 4
#define KQ    2048
#define NP    4096
#define CIN   64
#define CMID  32
#define NB    16
#define PPT   16     // points per thread in select (NP/256)
#define NBINS 512
#define CANDCAP 1024
#define QPB   8      // queries per block in edge_mlp_e

typedef short   bf16x8  __attribute__((ext_vector_type(8)));
typedef float   floatx4 __attribute__((ext_vector_type(4)));

__device__ __forceinline__ unsigned short f2bf(float f) {
  unsigned u = __float_as_uint(f);
  u = (u + 0x7fffu + ((u >> 16) & 1u)) >> 16;   // RNE, inputs finite
  return (unsigned short)u;
}

// ---------------------------------------------------------------------------
// Kernel 1: radix-select top-16 per query -> nidx[8192][16] (set order only;
// einsum sums over n so order is irrelevant; boundary ties -> lower index).
// ---------------------------------------------------------------------------
__global__ __launch_bounds__(256) void select_topk(
    const float* __restrict__ keys, const float* __restrict__ points,
    int* __restrict__ nidx_g) {
  __shared__ int   hist[NBINS];
  __shared__ float cand_d[CANDCAP];
  __shared__ int   cand_i[CANDCAP];
  __shared__ int   nidx[NB];
  __shared__ int   sel_cnt, cand_cnt, sBin, sCbelow;

  const int tid = threadIdx.x;
  const int b   = blockIdx.x >> 11;

  for (int i = tid; i < NBINS; i += 256) hist[i] = 0;
  if (tid == 0) { sel_cnt = 0; cand_cnt = 0; }

  const float kx = keys[blockIdx.x * 3 + 0];
  const float ky = keys[blockIdx.x * 3 + 1];
  const float kz = keys[blockIdx.x * 3 + 2];
  __syncthreads();

  float dreg[PPT];
#pragma unroll
  for (int t = 0; t < PPT; ++t) {
    const int i = tid + t * 256;
    const float* p = points + ((size_t)b * NP + i) * 3;
    float dx = p[0] - kx, dy = p[1] - ky, dz = p[2] - kz;
    float d = dx * dx + dy * dy + dz * dz;
    dreg[t] = d;
    atomicAdd(&hist[__float_as_uint(d) >> 22], 1);
  }
  __syncthreads();

  if (tid < 64) {
    const int base = tid * 8;
    int c[8]; int s = 0;
#pragma unroll
    for (int j = 0; j < 8; ++j) { c[j] = hist[base + j]; s += c[j]; }
    int incl = s;
#pragma unroll
    for (int off = 1; off < 64; off <<= 1) {
      int u = __shfl_up(incl, off);
      if (tid >= off) incl += u;
    }
    unsigned long long bal = __ballot(incl >= NB);
    int firstlane = __ffsll((long long)bal) - 1;
    if (tid == firstlane) {
      int cum = incl - s;
      int B = base;
#pragma unroll
      for (int j = 0; j < 8; ++j) {
        if (cum + c[j] >= NB) { B = base + j; break; }
        cum += c[j];
      }
      sBin = B; sCbelow = cum;
    }
  }
  __syncthreads();

  const unsigned B = (unsigned)sBin;
#pragma unroll
  for (int t = 0; t < PPT; ++t) {
    const int i = tid + t * 256;
    const unsigned bk = __float_as_uint(dreg[t]) >> 22;
    if (bk < B) {
      int pos = atomicAdd(&sel_cnt, 1);
      nidx[pos] = i;
    } else if (bk == B) {
      int pos = atomicAdd(&cand_cnt, 1);
      if (pos < CANDCAP) { cand_d[pos] = dreg[t]; cand_i[pos] = i; }
    }
  }
  __syncthreads();

  if (tid < 64) {
    const int rem = NB - sCbelow;
    const int cc  = min(cand_cnt, CANDCAP);
    for (int s = 0; s < rem; ++s) {
      float bd = FLT_MAX; int bi = INT_MAX; int bp = -1;
      for (int j = tid; j < cc; j += 64) {
        float d = cand_d[j]; int ii = cand_i[j];
        if (d < bd || (d == bd && ii < bi)) { bd = d; bi = ii; bp = j; }
      }
#pragma unroll
      for (int off = 32; off > 0; off >>= 1) {
        float od = __shfl_down(bd, off);
        int   oi = __shfl_down(bi, off);
        int   op = __shfl_down(bp, off);
        if (od < bd || (od == bd && oi < bi)) { bd = od; bi = oi; bp = op; }
      }
      if (tid == 0) { nidx[sCbelow + s] = bi; cand_d[bp] = FLT_MAX; }
    }
  }
  __syncthreads();

  if (tid < NB) nidx_g[blockIdx.x * NB + tid] = nidx[tid];
}

// ---------------------------------------------------------------------------
// Kernel 2: edge-parallel MLP + aggregation. 8 queries/block, 1 thread/edge
// (128 edges), weight LDS reads are wave-uniform (broadcast, conflict-free).
// e[q][mid*64+c] = sum_n m[q][n][mid] * f[q][n][c], written as bf16.
// ---------------------------------------------------------------------------
__global__ __launch_bounds__(256) void edge_mlp_e(
    const float* __restrict__ keys, const float* __restrict__ points,
    const float* __restrict__ feats, const int* __restrict__ nidx_g,
    const float* __restrict__ wc0_W, const float* __restrict__ wc0_b,
    const float* __restrict__ wc1_W, const float* __restrict__ wc1_b,
    const float* __restrict__ wc2_W, const float* __restrict__ wc2_b,
    unsigned short* __restrict__ E) {
  __shared__ float w0[96], b0v[32], w1[1024], b1v[32], w2[1024], b2v[32];
  __shared__ int   idx_s[QPB * NB];                 // 128
  __shared__ float m_all[QPB * NB][CMID + 1];       // stride 33: +1 breaks 32-bank alias
  __shared__ __align__(16) float f_all[QPB * NB][CIN + 4]; // stride 68 f32: 272B, 16B-aligned

  const int tid = threadIdx.x;
  const int q0  = blockIdx.x * QPB;
  const int b   = q0 >> 11;

  if (tid < 96) w0[tid] = wc0_W[tid];
  for (int i = tid; i < 1024; i += 256) { w1[i] = wc1_W[i]; w2[i] = wc2_W[i]; }
  if (tid < 32) { b0v[tid] = wc0_b[tid]; b1v[tid] = wc1_b[tid]; b2v[tid] = wc2_b[tid]; }
  if (tid < QPB * NB) idx_s[tid] = nidx_g[q0 * NB + tid];
  __syncthreads();

  if (tid < QPB * NB) {
    // one edge per thread: q = tid>>4, n = tid&15
    const int q   = tid >> 4;
    const int idx = idx_s[tid];
    const float* p  = points + ((size_t)b * NP + idx) * 3;
    const float* kq = keys + (size_t)(q0 + q) * 3;
    const float rx = p[0] - kq[0], ry = p[1] - kq[1], rz = p[2] - kq[2];
    float h1[32], h2[32];
#pragma unroll
    for (int o = 0; o < 32; ++o)
      h1[o] = fmaxf(0.f, rx * w0[o] + ry * w0[32 + o] + rz * w0[64 + o] + b0v[o]);
#pragma unroll
    for (int o = 0; o < 32; ++o) {
      float a = b1v[o];
#pragma unroll
      for (int i = 0; i < 32; ++i) a += h1[i] * w1[i * 32 + o];
      h2[o] = fmaxf(0.f, a);
    }
#pragma unroll
    for (int o = 0; o < 32; ++o) {
      float a = b2v[o];
#pragma unroll
      for (int i = 0; i < 32; ++i) a += h2[i] * w2[i * 32 + o];
      m_all[tid][o] = a;
    }
  } else {
    // threads 128..255 stage neighbor features (f32, padded rows)
    const int u  = tid - 128;       // 0..127
    const int cq = u & 15;          // c-quad
    for (int p = (u >> 4); p < QPB * NB; p += 8) {
      const int idx = idx_s[p];
      const float4 v = *reinterpret_cast<const float4*>(
          feats + ((size_t)b * NP + idx) * CIN + cq * 4);
      *reinterpret_cast<float4*>(&f_all[p][cq * 4]) = v;
    }
  }
  __syncthreads();

  // e-comp: group g = tid>>4 takes (q,mid) pairs; lane cq = tid&15 takes c-quad
  const int g  = tid >> 4;
  const int cq = tid & 15;
  for (int p = g; p < QPB * CMID; p += 16) {
    const int q = p >> 5, mid = p & 31;
    float4 a = {0.f, 0.f, 0.f, 0.f};
#pragma unroll
    for (int n = 0; n < NB; ++n) {
      const float mv = m_all[q * NB + n][mid];
      const float4 fv = *reinterpret_cast<const float4*>(&f_all[q * NB + n][cq * 4]);
      a.x += mv * fv.x; a.y += mv * fv.y; a.z += mv * fv.z; a.w += mv * fv.w;
    }
    ushort4 o;
    o.x = f2bf(a.x); o.y = f2bf(a.y); o.z = f2bf(a.z); o.w = f2bf(a.w);
    *reinterpret_cast<ushort4*>(&E[(size_t)(q0 + q) * 2048 + mid * 64 + cq * 4]) = o;
  }
}

// ---------------------------------------------------------------------------
// Kernel 3: W0 [2048][256] f32 -> W0T [256][2048] bf16 (LDS tile transpose)
// ---------------------------------------------------------------------------
__global__ __launch_bounds__(256) void transpose_w0(
    const float* __restrict__ W, unsigned short* __restrict__ WT) {
  __shared__ float t[32][33];
  const int k0 = blockIdx.x * 32, n0 = blockIdx.y * 32;
  const int tx = threadIdx.x & 31, ty = threadIdx.x >> 5;   // 8 rows/pass
#pragma unroll
  for (int p = 0; p < 4; ++p)
    t[ty + p * 8][tx] = W[(size_t)(k0 + ty + p * 8) * 256 + n0 + tx];
  __syncthreads();
#pragma unroll
  for (int p = 0; p < 4; ++p) {
    const int ny = ty + p * 8;
    WT[(size_t)(n0 + ny) * 2048 + k0 + tx] = f2bf(t[tx][ny]);
  }
}

// ---------------------------------------------------------------------------
// Kernel 4: MFMA GEMM  H = relu(E[M,K]bf16 @ W0 + b0), W given as W0T[N][K]bf16.
// 64x64 tile/block (256 thr = 4 waves, each 32x32 via 2x2 frags), BK=64.
// ---------------------------------------------------------------------------
__global__ __launch_bounds__(256) void gemm1_mfma(
    const unsigned short* __restrict__ A,   // [8192][2048] bf16
    const unsigned short* __restrict__ Bt,  // [256][2048]  bf16 (W0T)
    const float* __restrict__ bias, float* __restrict__ C) {
  // row stride 72 bf16 = 144 B: 16B-aligned, rotates banks by 4 per row
  __shared__ __align__(16) unsigned short Al[64][72];
  __shared__ __align__(16) unsigned short Bl[64][72];
  const int tid  = threadIdx.x;
  const int m0   = blockIdx.x * 64, n0 = blockIdx.y * 64;
  const int wave = tid >> 6, lane = tid & 63;
  const int quad = lane >> 4, s = lane & 15;
  const int moff = (wave & 1) * 32, noff = (wave >> 1) * 32;
  const int row_l = tid >> 3, col16 = tid & 7;   // staging: 32 rows x 8 uint4 per pass

  floatx4 acc[2][2] = {{{0.f,0.f,0.f,0.f},{0.f,0.f,0.f,0.f}},
                       {{0.f,0.f,0.f,0.f},{0.f,0.f,0.f,0.f}}};

  const uint4* Ag = reinterpret_cast<const uint4*>(A);
  const uint4* Bg = reinterpret_cast<const uint4*>(Bt);

  for (int k0 = 0; k0 < 2048; k0 += 64) {
    const int kq = k0 >> 3;   // uint4 units (8 bf16)
    *reinterpret_cast<uint4*>(&Al[row_l     ][col16 * 8]) = Ag[(size_t)(m0 + row_l     ) * 256 + kq + col16];
    *reinterpret_cast<uint4*>(&Al[row_l + 32][col16 * 8]) = Ag[(size_t)(m0 + row_l + 32) * 256 + kq + col16];
    *reinterpret_cast<uint4*>(&Bl[row_l     ][col16 * 8]) = Bg[(size_t)(n0 + row_l     ) * 256 + kq + col16];
    *reinterpret_cast<uint4*>(&Bl[row_l + 32][col16 * 8]) = Bg[(size_t)(n0 + row_l + 32) * 256 + kq + col16];
    __syncthreads();
#pragma unroll
    for (int h = 0; h < 2; ++h) {
      bf16x8 af[2], bfr[2];
#pragma unroll
      for (int i = 0; i < 2; ++i)
        af[i] = *reinterpret_cast<const bf16x8*>(&Al[moff + i * 16 + s][h * 32 + quad * 8]);
#pragma unroll
      for (int j = 0; j < 2; ++j)
        bfr[j] = *reinterpret_cast<const bf16x8*>(&Bl[noff + j * 16 + s][h * 32 + quad * 8]);
#pragma unroll
      for (int i = 0; i < 2; ++i)
#pragma unroll
        for (int j = 0; j < 2; ++j)
          acc[i][j] = __builtin_amdgcn_mfma_f32_16x16x32_bf16(af[i], bfr[j], acc[i][j], 0, 0, 0);
    }
    __syncthreads();
  }

#pragma unroll
  for (int i = 0; i < 2; ++i)
#pragma unroll
    for (int j = 0; j < 2; ++j) {
      const int col = n0 + noff + j * 16 + s;
      const float bv = bias[col];
#pragma unroll
      for (int r = 0; r < 4; ++r) {
        const int row = m0 + moff + i * 16 + quad * 4 + r;
        C[(size_t)row * 256 + col] = fmaxf(acc[i][j][r] + bv, 0.f);
      }
    }
}

// ---------------------------------------------------------------------------
// Kernel 5: fp32 tiled GEMM (fc1, small): C = A[M,256] @ W[256,128] + bias
// ---------------------------------------------------------------------------
__global__ __launch_bounds__(256) void gemm_bias_f32(
    const float* __restrict__ A, const float* __restrict__ W,
    const float* __restrict__ bias, float* __restrict__ C,
    int M, int K, int N) {
  __shared__ __align__(16) float a_t[32][68];
  __shared__ __align__(16) float b_t[32][68];
  const int tid = threadIdx.x;
  const int m0 = blockIdx.x * 64;
  const int n0 = blockIdx.y * 64;
  const int tr = tid >> 4, tc = tid & 15;
  const int r0 = tr * 4, c0 = tc * 4;

  float acc[4][4] = {};

  for (int k0 = 0; k0 < K; k0 += 32) {
#pragma unroll
    for (int t = 0; t < 8; ++t) {
      int j = tid + t * 256;
      int r = j >> 5, kk = j & 31;
      a_t[kk][r] = A[(size_t)(m0 + r) * K + (k0 + kk)];
      int kk2 = j >> 6, c = j & 63;
      b_t[kk2][c] = W[(size_t)(k0 + kk2) * N + (n0 + c)];
    }
    __syncthreads();
#pragma unroll
    for (int kk = 0; kk < 32; ++kk) {
      float4 av = *reinterpret_cast<const float4*>(&a_t[kk][r0]);
      float4 bv = *reinterpret_cast<const float4*>(&b_t[kk][c0]);
      float ar[4] = {av.x, av.y, av.z, av.w};
      float br[4] = {bv.x, bv.y, bv.z, bv.w};
#pragma unroll
      for (int i = 0; i < 4; ++i)
#pragma unroll
        for (int j = 0; j < 4; ++j) acc[i][j] += ar[i] * br[j];
    }
    __syncthreads();
  }

#pragma unroll
  for (int i = 0; i < 4; ++i) {
    float4 o;
#pragma unroll
    for (int j = 0; j < 4; ++j) (&o.x)[j] = acc[i][j] + bias[n0 + c0 + j];
    *reinterpret_cast<float4*>(&C[(size_t)(m0 + r0 + i) * N + (n0 + c0)]) = o;
  }
}

// ---------------------------------------------------------------------------
extern "C" void kernel_launch(void* const* d_in, const int* in_sizes, int n_in,
                              void* d_out, int out_size, void* d_ws, size_t ws_size,
                              hipStream_t stream) {
  const float* keys   = (const float*)d_in[0];
  const float* points = (const float*)d_in[1];
  const float* feats  = (const float*)d_in[2];
  const float* wc0_W  = (const float*)d_in[3];
  const float* wc0_b  = (const float*)d_in[4];
  const float* wc1_W  = (const float*)d_in[5];
  const float* wc1_b  = (const float*)d_in[6];
  const float* wc2_W  = (const float*)d_in[7];
  const float* wc2_b  = (const float*)d_in[8];
  const float* fc0_W  = (const float*)d_in[9];
  const float* fc0_b  = (const float*)d_in[10];
  const float* fc1_W  = (const float*)d_in[11];
  const float* fc1_b  = (const float*)d_in[12];
  float* out = (float*)d_out;

  const int M = BATCH * KQ;   // 8192
  char* ws = (char*)d_ws;
  unsigned short* E   = (unsigned short*)(ws);                      // 32 MB bf16
  float*          H   = (float*)(ws + (size_t)33554432);            //  8 MB f32
  unsigned short* W0T = (unsigned short*)(ws + (size_t)41943040);   //  1 MB bf16
  int*            nidx = (int*)(ws + (size_t)42991616);             // 512 KB

  select_topk<<<M, 256, 0, stream>>>(keys, points, nidx);
  transpose_w0<<<dim3(64, 8), 256, 0, stream>>>(fc0_W, W0T);
  edge_mlp_e<<<M / QPB, 256, 0, stream>>>(keys, points, feats, nidx,
                                          wc0_W, wc0_b, wc1_W, wc1_b, wc2_W, wc2_b, E);
  gemm1_mfma<<<dim3(M / 64, 4), 256, 0, stream>>>(E, W0T, fc0_b, H);
  gemm_bias_f32<<<dim3(M / 64, 2), 256, 0, stream>>>(H, fc1_W, fc1_b, out,
                                                     M, 256, 128);
}

// Round 4
// 187.767 us; speedup vs baseline: 4.8425x; 1.2951x over previous
//
#include <hip/hip_runtime.h>
#include <cfloat>
#include <climits>

#define BATCH 4
#define KQ    2048
#define NP    4096
#define CIN   64
#define CMID  32
#define NB    16
#define NBINS 4096   // bits >> 19 : 8 exp bits + 4 mantissa bits
#define CANDCAP 256
#define QPB   8      // queries per block in edge_mlp_e

typedef short   bf16x8  __attribute__((ext_vector_type(8)));
typedef float   floatx4 __attribute__((ext_vector_type(4)));

__device__ __forceinline__ unsigned short f2bf(float f) {
  unsigned u = __float_as_uint(f);
  u = (u + 0x7fffu + ((u >> 16) & 1u)) >> 16;   // RNE, inputs finite
  return (unsigned short)u;
}

// async global->LDS, 16B per lane; LDS dst = base + lane*16 (wave-uniform base)
__device__ __forceinline__ void load_lds16(const void* g, void* l) {
  __builtin_amdgcn_global_load_lds(
      (const __attribute__((address_space(1))) unsigned int*)g,
      (__attribute__((address_space(3))) unsigned int*)l, 16, 0, 0);
}

// ---------------------------------------------------------------------------
// Kernel 1: radix-select top-16 per query -> nidx[8192][16] (set only; the
// einsum sums over n so order is irrelevant; boundary ties -> lower index).
// 4096 bins (exp + 4 mantissa bits) spread the LDS-atomic hot spots 16x vs
// the 512-bin version (SQ_LDS_BANK_CONFLICT was 7.35M there).
// ---------------------------------------------------------------------------
__global__ __launch_bounds__(256) void select_topk(
    const float* __restrict__ keys, const float* __restrict__ points,
    int* __restrict__ nidx_g) {
  __shared__ int   hist[NBINS];            // 16 KB
  __shared__ int   psum[256];
  __shared__ float cand_d[CANDCAP];
  __shared__ int   cand_i[CANDCAP];
  __shared__ int   nidx[NB];
  __shared__ int   sel_cnt, cand_cnt, sBin, sCbelow;

  const int tid = threadIdx.x;
  const int b   = blockIdx.x >> 11;

  for (int i = tid; i < NBINS; i += 256) hist[i] = 0;
  if (tid == 0) { sel_cnt = 0; cand_cnt = 0; }

  const float kx = keys[blockIdx.x * 3 + 0];
  const float ky = keys[blockIdx.x * 3 + 1];
  const float kz = keys[blockIdx.x * 3 + 2];
  __syncthreads();

  // pass 1: thread owns 16 consecutive points (12 float4 loads), histograms
  const float4* pv =
      reinterpret_cast<const float4*>(points + (size_t)b * NP * 3) + (size_t)tid * 12;
  float f[48];
#pragma unroll
  for (int c = 0; c < 12; ++c) {
    const float4 v = pv[c];
    f[c * 4 + 0] = v.x; f[c * 4 + 1] = v.y; f[c * 4 + 2] = v.z; f[c * 4 + 3] = v.w;
  }
  float dreg[16];
#pragma unroll
  for (int j = 0; j < 16; ++j) {
    const float dx = f[j * 3 + 0] - kx;
    const float dy = f[j * 3 + 1] - ky;
    const float dz = f[j * 3 + 2] - kz;
    const float d  = dx * dx + dy * dy + dz * dz;
    dreg[j] = d;
    atomicAdd(&hist[__float_as_uint(d) >> 19], 1);
  }
  __syncthreads();

  // two-level threshold scan: per-thread 16-bin sums -> wave-0 shuffle scan
  {
    const int base = tid * 16;
    int s = 0;
#pragma unroll
    for (int j = 0; j < 16; ++j) s += hist[base + j];
    psum[tid] = s;
  }
  __syncthreads();

  if (tid < 64) {
    const int q = psum[tid * 4] + psum[tid * 4 + 1] + psum[tid * 4 + 2] + psum[tid * 4 + 3];
    int incl = q;
#pragma unroll
    for (int off = 1; off < 64; off <<= 1) {
      int u = __shfl_up(incl, off);
      if (tid >= off) incl += u;
    }
    unsigned long long bal = __ballot(incl >= NB);
    int firstlane = __ffsll((long long)bal) - 1;
    if (tid == firstlane) {
      int cum = incl - q;
      int bin = -1;
      for (int t = 0; t < 4 && bin < 0; ++t) {
        const int ps = psum[tid * 4 + t];
        if (cum + ps >= NB) {
          const int b0 = (tid * 4 + t) * 16;
          for (int j = 0; j < 16; ++j) {
            const int h = hist[b0 + j];
            if (cum + h >= NB) { bin = b0 + j; break; }
            cum += h;
          }
        } else cum += ps;
      }
      sBin = bin; sCbelow = cum;
    }
  }
  __syncthreads();

  const unsigned B = (unsigned)sBin;
#pragma unroll
  for (int j = 0; j < 16; ++j) {
    const int i = tid * 16 + j;
    const unsigned bk = __float_as_uint(dreg[j]) >> 19;
    if (bk < B) {
      int pos = atomicAdd(&sel_cnt, 1);
      nidx[pos] = i;                       // pos < 16 guaranteed (Cbelow < 16)
    } else if (bk == B) {
      int pos = atomicAdd(&cand_cnt, 1);
      if (pos < CANDCAP) { cand_d[pos] = dreg[j]; cand_i[pos] = i; }
    }
  }
  __syncthreads();

  if (tid < 64) {
    const int rem = NB - sCbelow;
    const int cc  = min(cand_cnt, CANDCAP);
    for (int s = 0; s < rem; ++s) {
      float bd = FLT_MAX; int bi = INT_MAX; int bp = -1;
      for (int j = tid; j < cc; j += 64) {
        float d = cand_d[j]; int ii = cand_i[j];
        if (d < bd || (d == bd && ii < bi)) { bd = d; bi = ii; bp = j; }
      }
#pragma unroll
      for (int off = 32; off > 0; off >>= 1) {
        float od = __shfl_down(bd, off);
        int   oi = __shfl_down(bi, off);
        int   op = __shfl_down(bp, off);
        if (od < bd || (od == bd && oi < bi)) { bd = od; bi = oi; bp = op; }
      }
      if (tid == 0) { nidx[sCbelow + s] = bi; cand_d[bp] = FLT_MAX; }
    }
  }
  __syncthreads();

  if (tid < NB) nidx_g[blockIdx.x * NB + tid] = nidx[tid];
}

// ---------------------------------------------------------------------------
// Kernel 2: edge-parallel MLP + aggregation -> E bf16 (unchanged from R3)
// ---------------------------------------------------------------------------
__global__ __launch_bounds__(256) void edge_mlp_e(
    const float* __restrict__ keys, const float* __restrict__ points,
    const float* __restrict__ feats, const int* __restrict__ nidx_g,
    const float* __restrict__ wc0_W, const float* __restrict__ wc0_b,
    const float* __restrict__ wc1_W, const float* __restrict__ wc1_b,
    const float* __restrict__ wc2_W, const float* __restrict__ wc2_b,
    unsigned short* __restrict__ E) {
  __shared__ float w0[96], b0v[32], w1[1024], b1v[32], w2[1024], b2v[32];
  __shared__ int   idx_s[QPB * NB];
  __shared__ float m_all[QPB * NB][CMID + 1];
  __shared__ __align__(16) float f_all[QPB * NB][CIN + 4];

  const int tid = threadIdx.x;
  const int q0  = blockIdx.x * QPB;
  const int b   = q0 >> 11;

  if (tid < 96) w0[tid] = wc0_W[tid];
  for (int i = tid; i < 1024; i += 256) { w1[i] = wc1_W[i]; w2[i] = wc2_W[i]; }
  if (tid < 32) { b0v[tid] = wc0_b[tid]; b1v[tid] = wc1_b[tid]; b2v[tid] = wc2_b[tid]; }
  if (tid < QPB * NB) idx_s[tid] = nidx_g[q0 * NB + tid];
  __syncthreads();

  if (tid < QPB * NB) {
    const int q   = tid >> 4;
    const int idx = idx_s[tid];
    const float* p  = points + ((size_t)b * NP + idx) * 3;
    const float* kq = keys + (size_t)(q0 + q) * 3;
    const float rx = p[0] - kq[0], ry = p[1] - kq[1], rz = p[2] - kq[2];
    float h1[32], h2[32];
#pragma unroll
    for (int o = 0; o < 32; ++o)
      h1[o] = fmaxf(0.f, rx * w0[o] + ry * w0[32 + o] + rz * w0[64 + o] + b0v[o]);
#pragma unroll
    for (int o = 0; o < 32; ++o) {
      float a = b1v[o];
#pragma unroll
      for (int i = 0; i < 32; ++i) a += h1[i] * w1[i * 32 + o];
      h2[o] = fmaxf(0.f, a);
    }
#pragma unroll
    for (int o = 0; o < 32; ++o) {
      float a = b2v[o];
#pragma unroll
      for (int i = 0; i < 32; ++i) a += h2[i] * w2[i * 32 + o];
      m_all[tid][o] = a;
    }
  } else {
    const int u  = tid - 128;
    const int cq = u & 15;
    for (int p = (u >> 4); p < QPB * NB; p += 8) {
      const int idx = idx_s[p];
      const float4 v = *reinterpret_cast<const float4*>(
          feats + ((size_t)b * NP + idx) * CIN + cq * 4);
      *reinterpret_cast<float4*>(&f_all[p][cq * 4]) = v;
    }
  }
  __syncthreads();

  const int g  = tid >> 4;
  const int cq = tid & 15;
  for (int p = g; p < QPB * CMID; p += 16) {
    const int q = p >> 5, mid = p & 31;
    float4 a = {0.f, 0.f, 0.f, 0.f};
#pragma unroll
    for (int n = 0; n < NB; ++n) {
      const float mv = m_all[q * NB + n][mid];
      const float4 fv = *reinterpret_cast<const float4*>(&f_all[q * NB + n][cq * 4]);
      a.x += mv * fv.x; a.y += mv * fv.y; a.z += mv * fv.z; a.w += mv * fv.w;
    }
    ushort4 o;
    o.x = f2bf(a.x); o.y = f2bf(a.y); o.z = f2bf(a.z); o.w = f2bf(a.w);
    *reinterpret_cast<ushort4*>(&E[(size_t)(q0 + q) * 2048 + mid * 64 + cq * 4]) = o;
  }
}

// ---------------------------------------------------------------------------
// Kernel 3: generic W[K][N] f32 -> WT[N][K] bf16 tile transpose
// ---------------------------------------------------------------------------
__global__ __launch_bounds__(256) void transpose_bf16(
    const float* __restrict__ W, unsigned short* __restrict__ WT,
    int K, int N) {
  __shared__ float t[32][33];
  const int k0 = blockIdx.x * 32, n0 = blockIdx.y * 32;
  const int tx = threadIdx.x & 31, ty = threadIdx.x >> 5;
#pragma unroll
  for (int p = 0; p < 4; ++p)
    t[ty + p * 8][tx] = W[(size_t)(k0 + ty + p * 8) * N + n0 + tx];
  __syncthreads();
#pragma unroll
  for (int p = 0; p < 4; ++p)
    WT[(size_t)(n0 + ty + p * 8) * K + k0 + tx] = f2bf(t[tx][ty + p * 8]);
}

// ---------------------------------------------------------------------------
// Kernel 4/5: MFMA GEMM  C = act(A[M,KDIM]bf16 @ Bt[N,KDIM]^T + bias)
// 64x64 tile (4 waves x 32x32), BK=128, global_load_lds width-16 staging,
// XOR chunk swizzle (chunk ^= row&7) for conflict-free ds_read_b128 (padding
// is incompatible with global_load_lds's base+lane*16 scatter).
// ---------------------------------------------------------------------------
template <int KDIM, bool RELU, bool OUTBF16>
__global__ __launch_bounds__(256) void gemm_mfma(
    const unsigned short* __restrict__ A,   // [M][KDIM] bf16
    const unsigned short* __restrict__ Bt,  // [N][KDIM] bf16
    const float* __restrict__ bias,
    void* __restrict__ Cout, int ldc) {
  __shared__ __align__(16) unsigned short Al[64 * 128];  // 16 KB
  __shared__ __align__(16) unsigned short Bl[64 * 128];  // 16 KB
  const int tid  = threadIdx.x;
  const int m0   = blockIdx.x * 64, n0 = blockIdx.y * 64;
  const int wv   = tid >> 6, lane = tid & 63;
  const int quad = lane >> 4, s = lane & 15;
  const int moff = (wv & 1) * 32, noff = (wv >> 1) * 32;
  const int lr   = lane >> 4;     // staging: row within 4-row group
  const int lc   = lane & 15;     // staging: 16B chunk within row

  floatx4 acc[2][2] = {{{0.f,0.f,0.f,0.f},{0.f,0.f,0.f,0.f}},
                       {{0.f,0.f,0.f,0.f},{0.f,0.f,0.f,0.f}}};

  for (int k0 = 0; k0 < KDIM; k0 += 128) {
#pragma unroll
    for (int t = 0; t < 4; ++t) {
      const int R0 = wv * 16 + t * 4;          // wave-uniform base row
      const int r  = R0 + lr;
      const int gc = lc ^ (r & 7);             // lane lc lands at LDS chunk lc;
                                               // fetch swizzled source chunk
      load_lds16(A  + (size_t)(m0 + r) * KDIM + k0 + gc * 8, &Al[R0 * 128]);
      load_lds16(Bt + (size_t)(n0 + r) * KDIM + k0 + gc * 8, &Bl[R0 * 128]);
    }
    __syncthreads();
#pragma unroll
    for (int h = 0; h < 4; ++h) {
      bf16x8 af[2], bfr[2];
#pragma unroll
      for (int i = 0; i < 2; ++i) {
        const int r = moff + i * 16 + s;
        af[i] = *reinterpret_cast<const bf16x8*>(
            &Al[(size_t)r * 128 + ((((h << 2) | quad) ^ (r & 7)) << 3)]);
      }
#pragma unroll
      for (int j = 0; j < 2; ++j) {
        const int r = noff + j * 16 + s;
        bfr[j] = *reinterpret_cast<const bf16x8*>(
            &Bl[(size_t)r * 128 + ((((h << 2) | quad) ^ (r & 7)) << 3)]);
      }
#pragma unroll
      for (int i = 0; i < 2; ++i)
#pragma unroll
        for (int j = 0; j < 2; ++j)
          acc[i][j] = __builtin_amdgcn_mfma_f32_16x16x32_bf16(af[i], bfr[j], acc[i][j], 0, 0, 0);
    }
    __syncthreads();
  }

#pragma unroll
  for (int i = 0; i < 2; ++i)
#pragma unroll
    for (int j = 0; j < 2; ++j) {
      const int col = n0 + noff + j * 16 + s;
      const float bv = bias[col];
#pragma unroll
      for (int r = 0; r < 4; ++r) {
        const int row = m0 + moff + i * 16 + quad * 4 + r;
        float v = acc[i][j][r] + bv;
        if (RELU) v = fmaxf(v, 0.f);
        if (OUTBF16)
          ((unsigned short*)Cout)[(size_t)row * ldc + col] = f2bf(v);
        else
          ((float*)Cout)[(size_t)row * ldc + col] = v;
      }
    }
}

// ---------------------------------------------------------------------------
extern "C" void kernel_launch(void* const* d_in, const int* in_sizes, int n_in,
                              void* d_out, int out_size, void* d_ws, size_t ws_size,
                              hipStream_t stream) {
  const float* keys   = (const float*)d_in[0];
  const float* points = (const float*)d_in[1];
  const float* feats  = (const float*)d_in[2];
  const float* wc0_W  = (const float*)d_in[3];
  const float* wc0_b  = (const float*)d_in[4];
  const float* wc1_W  = (const float*)d_in[5];
  const float* wc1_b  = (const float*)d_in[6];
  const float* wc2_W  = (const float*)d_in[7];
  const float* wc2_b  = (const float*)d_in[8];
  const float* fc0_W  = (const float*)d_in[9];
  const float* fc0_b  = (const float*)d_in[10];
  const float* fc1_W  = (const float*)d_in[11];
  const float* fc1_b  = (const float*)d_in[12];
  float* out = (float*)d_out;

  const int M = BATCH * KQ;   // 8192
  char* ws = (char*)d_ws;
  unsigned short* E    = (unsigned short*)(ws);                    // 32 MB
  unsigned short* H16  = (unsigned short*)(ws + (size_t)33554432); //  4 MB
  unsigned short* W0T  = (unsigned short*)(ws + (size_t)37748736); //  1 MB
  unsigned short* W1T  = (unsigned short*)(ws + (size_t)38797312); // 64 KB
  int*            nidx = (int*)(ws + (size_t)38862848);            // 512 KB

  select_topk<<<M, 256, 0, stream>>>(keys, points, nidx);
  transpose_bf16<<<dim3(64, 8), 256, 0, stream>>>(fc0_W, W0T, 2048, 256);
  transpose_bf16<<<dim3(8, 4), 256, 0, stream>>>(fc1_W, W1T, 256, 128);
  edge_mlp_e<<<M / QPB, 256, 0, stream>>>(keys, points, feats, nidx,
                                          wc0_W, wc0_b, wc1_W, wc1_b, wc2_W, wc2_b, E);
  gemm_mfma<2048, true,  true ><<<dim3(M / 64, 4), 256, 0, stream>>>(E, W0T, fc0_b, H16, 256);
  gemm_mfma<256,  false, false><<<dim3(M / 64, 2), 256, 0, stream>>>(H16, W1T, fc1_b, out, 128);
}

// Round 5
// 184.121 us; speedup vs baseline: 4.9384x; 1.0198x over previous
//
#include <hip/hip_runtime.h>
#include <cfloat>
#include <climits>

#define BATCH 4
#define KQ    2048
#define NP    4096
#define CIN   64
#define CMID  32
#define NB    16
#define NBINS 4096   // bits >> 19 : 8 exp bits + 4 mantissa bits
#define CANDCAP 256
#define QPB   8      // queries per block in edge_mlp_e

typedef short   bf16x8  __attribute__((ext_vector_type(8)));
typedef float   floatx4 __attribute__((ext_vector_type(4)));

__device__ __forceinline__ unsigned short f2bf(float f) {
  unsigned u = __float_as_uint(f);
  u = (u + 0x7fffu + ((u >> 16) & 1u)) >> 16;   // RNE, inputs finite
  return (unsigned short)u;
}
__device__ __forceinline__ float bf2f(unsigned short u) {
  return __uint_as_float((unsigned)u << 16);
}

// async global->LDS, 16B per lane; LDS dst = base + lane*16 (wave-uniform base)
__device__ __forceinline__ void load_lds16(const void* g, void* l) {
  __builtin_amdgcn_global_load_lds(
      (const __attribute__((address_space(1))) unsigned int*)g,
      (__attribute__((address_space(3))) unsigned int*)l, 16, 0, 0);
}

// ---------------------------------------------------------------------------
// Kernel 1: radix-select top-16 per query -> nidx[8192][16] (set only; the
// einsum sums over n so order is irrelevant; boundary ties -> lower index).
// ---------------------------------------------------------------------------
__global__ __launch_bounds__(256) void select_topk(
    const float* __restrict__ keys, const float* __restrict__ points,
    int* __restrict__ nidx_g) {
  __shared__ int   hist[NBINS];            // 16 KB
  __shared__ int   psum[256];
  __shared__ float cand_d[CANDCAP];
  __shared__ int   cand_i[CANDCAP];
  __shared__ int   nidx[NB];
  __shared__ int   sel_cnt, cand_cnt, sBin, sCbelow;

  const int tid = threadIdx.x;
  const int b   = blockIdx.x >> 11;

  for (int i = tid; i < NBINS; i += 256) hist[i] = 0;
  if (tid == 0) { sel_cnt = 0; cand_cnt = 0; }

  const float kx = keys[blockIdx.x * 3 + 0];
  const float ky = keys[blockIdx.x * 3 + 1];
  const float kz = keys[blockIdx.x * 3 + 2];
  __syncthreads();

  // pass 1: thread owns 16 consecutive points (12 float4 loads), histograms
  const float4* pv =
      reinterpret_cast<const float4*>(points + (size_t)b * NP * 3) + (size_t)tid * 12;
  float f[48];
#pragma unroll
  for (int c = 0; c < 12; ++c) {
    const float4 v = pv[c];
    f[c * 4 + 0] = v.x; f[c * 4 + 1] = v.y; f[c * 4 + 2] = v.z; f[c * 4 + 3] = v.w;
  }
  float dreg[16];
#pragma unroll
  for (int j = 0; j < 16; ++j) {
    const float dx = f[j * 3 + 0] - kx;
    const float dy = f[j * 3 + 1] - ky;
    const float dz = f[j * 3 + 2] - kz;
    const float d  = dx * dx + dy * dy + dz * dz;
    dreg[j] = d;
    atomicAdd(&hist[__float_as_uint(d) >> 19], 1);
  }
  __syncthreads();

  // two-level threshold scan: per-thread 16-bin sums -> wave-0 shuffle scan
  {
    const int base = tid * 16;
    int s = 0;
#pragma unroll
    for (int j = 0; j < 16; ++j) s += hist[base + j];
    psum[tid] = s;
  }
  __syncthreads();

  if (tid < 64) {
    const int q = psum[tid * 4] + psum[tid * 4 + 1] + psum[tid * 4 + 2] + psum[tid * 4 + 3];
    int incl = q;
#pragma unroll
    for (int off = 1; off < 64; off <<= 1) {
      int u = __shfl_up(incl, off);
      if (tid >= off) incl += u;
    }
    unsigned long long bal = __ballot(incl >= NB);
    int firstlane = __ffsll((long long)bal) - 1;
    if (tid == firstlane) {
      int cum = incl - q;
      int bin = -1;
      for (int t = 0; t < 4 && bin < 0; ++t) {
        const int ps = psum[tid * 4 + t];
        if (cum + ps >= NB) {
          const int b0 = (tid * 4 + t) * 16;
          for (int j = 0; j < 16; ++j) {
            const int h = hist[b0 + j];
            if (cum + h >= NB) { bin = b0 + j; break; }
            cum += h;
          }
        } else cum += ps;
      }
      sBin = bin; sCbelow = cum;
    }
  }
  __syncthreads();

  const unsigned B = (unsigned)sBin;
#pragma unroll
  for (int j = 0; j < 16; ++j) {
    const int i = tid * 16 + j;
    const unsigned bk = __float_as_uint(dreg[j]) >> 19;
    if (bk < B) {
      int pos = atomicAdd(&sel_cnt, 1);
      nidx[pos] = i;
    } else if (bk == B) {
      int pos = atomicAdd(&cand_cnt, 1);
      if (pos < CANDCAP) { cand_d[pos] = dreg[j]; cand_i[pos] = i; }
    }
  }
  __syncthreads();

  if (tid < 64) {
    const int rem = NB - sCbelow;
    const int cc  = min(cand_cnt, CANDCAP);
    for (int s = 0; s < rem; ++s) {
      float bd = FLT_MAX; int bi = INT_MAX; int bp = -1;
      for (int j = tid; j < cc; j += 64) {
        float d = cand_d[j]; int ii = cand_i[j];
        if (d < bd || (d == bd && ii < bi)) { bd = d; bi = ii; bp = j; }
      }
#pragma unroll
      for (int off = 32; off > 0; off >>= 1) {
        float od = __shfl_down(bd, off);
        int   oi = __shfl_down(bi, off);
        int   op = __shfl_down(bp, off);
        if (od < bd || (od == bd && oi < bi)) { bd = od; bi = oi; bp = op; }
      }
      if (tid == 0) { nidx[sCbelow + s] = bi; cand_d[bp] = FLT_MAX; }
    }
  }
  __syncthreads();

  if (tid < NB) nidx_g[blockIdx.x * NB + tid] = nidx[tid];
}

// ---------------------------------------------------------------------------
// Kernel 2 (rebuilt): edge MLP + aggregation -> E bf16.
// All 256 threads active in every phase; f/m in LDS as bf16; h2 handoff
// buffer UNIONed with f staging (temporally disjoint). 37.3 KB LDS ->
// 4 blocks/CU. e-comp register-blocked: 4 mids x 8 ch per thread.
// ---------------------------------------------------------------------------
__global__ __launch_bounds__(256) void edge_mlp_e(
    const float* __restrict__ keys, const float* __restrict__ points,
    const float* __restrict__ feats, const int* __restrict__ nidx_g,
    const float* __restrict__ wc0_W, const float* __restrict__ wc0_b,
    const float* __restrict__ wc1_W, const float* __restrict__ wc1_b,
    const float* __restrict__ wc2_W, const float* __restrict__ wc2_b,
    unsigned short* __restrict__ E) {
  __shared__ float w0[96], b0v[32], w1[1024], b1v[32], w2[1024], b2v[32];
  __shared__ int   idx_s[QPB * NB];                              // 512 B
  __shared__ __align__(16) unsigned short m_bf[QPB * NB][40];    // 10 KB (row 80B)
  __shared__ __align__(16) char u_mem[128 * 144];                // 18 KB union
  float (*h2_all)[33]        = reinterpret_cast<float(*)[33]>(u_mem);
  unsigned short (*f_bf)[72] = reinterpret_cast<unsigned short(*)[72]>(u_mem);

  const int tid = threadIdx.x;
  const int q0  = blockIdx.x * QPB;
  const int b   = q0 >> 11;

  if (tid < 96) w0[tid] = wc0_W[tid];
  for (int i = tid; i < 1024; i += 256) { w1[i] = wc1_W[i]; w2[i] = wc2_W[i]; }
  if (tid < 32) { b0v[tid] = wc0_b[tid]; b1v[tid] = wc1_b[tid]; b2v[tid] = wc2_b[tid]; }
  if (tid < QPB * NB) idx_s[tid] = nidx_g[q0 * NB + tid];
  __syncthreads();

  // ---- MLP: thread (edge, half) computes h1 fully, h2/m for 16 outputs ----
  const int edge = tid & 127;
  const int half = tid >> 7;
  const int ob   = half * 16;
  const int qe   = edge >> 4;
  const int idx  = idx_s[edge];
  {
    const float* p  = points + ((size_t)b * NP + idx) * 3;
    const float* kq = keys + (size_t)(q0 + qe) * 3;
    const float rx = p[0] - kq[0], ry = p[1] - kq[1], rz = p[2] - kq[2];

    float h1[32];
#pragma unroll
    for (int o = 0; o < 32; ++o)
      h1[o] = fmaxf(0.f, rx * w0[o] + ry * w0[32 + o] + rz * w0[64 + o] + b0v[o]);
#pragma unroll
    for (int j = 0; j < 16; ++j) {
      const int o = ob + j;
      float a = b1v[o];
#pragma unroll
      for (int i = 0; i < 32; ++i) a += h1[i] * w1[i * 32 + o];
      h2_all[edge][o] = fmaxf(a, 0.f);
    }
  }
  __syncthreads();

  float mo[16];
#pragma unroll
  for (int j = 0; j < 16; ++j) {
    const int o = ob + j;
    float a = b2v[o];
#pragma unroll
    for (int i = 0; i < 32; ++i) a += h2_all[edge][i] * w2[i * 32 + o];
    mo[j] = a;
  }
  // write m (bf16 pairs packed into dwords) — separate LDS region, pre-barrier
#pragma unroll
  for (int j = 0; j < 8; ++j) {
    const unsigned lo = f2bf(mo[2 * j]), hi = f2bf(mo[2 * j + 1]);
    *reinterpret_cast<unsigned*>(&m_bf[edge][ob + 2 * j]) = lo | (hi << 16);
  }
  __syncthreads();   // h2 region dead from here; f staging may reuse u_mem

  // ---- stage neighbor features bf16: 128 rows x 16 float4-chunks ----
#pragma unroll
  for (int t = 0; t < 8; ++t) {
    const int task = tid + t * 256;          // 0..2047
    const int row = task >> 4, ch = task & 15;
    const float4 v = *reinterpret_cast<const float4*>(
        feats + ((size_t)b * NP + idx_s[row]) * CIN + ch * 4);
    ushort4 o4;
    o4.x = f2bf(v.x); o4.y = f2bf(v.y); o4.z = f2bf(v.z); o4.w = f2bf(v.w);
    *reinterpret_cast<ushort4*>(&f_bf[row][ch * 4]) = o4;
  }
  __syncthreads();

  // ---- e-comp: wave -> q, lane -> (mg: 4 mids, co: 8 ch), 2 q-iters ----
  const int wv = tid >> 6, lane = tid & 63;
  const int co = lane & 7, mg = lane >> 3;
#pragma unroll
  for (int it = 0; it < 2; ++it) {
    const int q = wv + it * 4;
    float acc[4][8] = {};
#pragma unroll
    for (int n = 0; n < 16; ++n) {
      const int row = q * 16 + n;
      const ushort4 m4 = *reinterpret_cast<const ushort4*>(&m_bf[row][mg * 4]);
      const float mv[4] = {bf2f(m4.x), bf2f(m4.y), bf2f(m4.z), bf2f(m4.w)};
      const uint4 fv = *reinterpret_cast<const uint4*>(&f_bf[row][co * 8]);
      float fc[8];
      fc[0] = __uint_as_float(fv.x << 16); fc[1] = __uint_as_float(fv.x & 0xffff0000u);
      fc[2] = __uint_as_float(fv.y << 16); fc[3] = __uint_as_float(fv.y & 0xffff0000u);
      fc[4] = __uint_as_float(fv.z << 16); fc[5] = __uint_as_float(fv.z & 0xffff0000u);
      fc[6] = __uint_as_float(fv.w << 16); fc[7] = __uint_as_float(fv.w & 0xffff0000u);
#pragma unroll
      for (int i = 0; i < 4; ++i)
#pragma unroll
        for (int j = 0; j < 8; ++j) acc[i][j] += mv[i] * fc[j];
    }
    unsigned short* Eq = E + (size_t)(q0 + q) * 2048;
#pragma unroll
    for (int i = 0; i < 4; ++i) {
      const int mid = mg * 4 + i;
      uint4 o;
      o.x = (unsigned)f2bf(acc[i][0]) | ((unsigned)f2bf(acc[i][1]) << 16);
      o.y = (unsigned)f2bf(acc[i][2]) | ((unsigned)f2bf(acc[i][3]) << 16);
      o.z = (unsigned)f2bf(acc[i][4]) | ((unsigned)f2bf(acc[i][5]) << 16);
      o.w = (unsigned)f2bf(acc[i][6]) | ((unsigned)f2bf(acc[i][7]) << 16);
      *reinterpret_cast<uint4*>(&Eq[mid * 64 + co * 8]) = o;
    }
  }
}

// ---------------------------------------------------------------------------
// Kernel 3: generic W[K][N] f32 -> WT[N][K] bf16 tile transpose
// ---------------------------------------------------------------------------
__global__ __launch_bounds__(256) void transpose_bf16(
    const float* __restrict__ W, unsigned short* __restrict__ WT,
    int K, int N) {
  __shared__ float t[32][33];
  const int k0 = blockIdx.x * 32, n0 = blockIdx.y * 32;
  const int tx = threadIdx.x & 31, ty = threadIdx.x >> 5;
#pragma unroll
  for (int p = 0; p < 4; ++p)
    t[ty + p * 8][tx] = W[(size_t)(k0 + ty + p * 8) * N + n0 + tx];
  __syncthreads();
#pragma unroll
  for (int p = 0; p < 4; ++p)
    WT[(size_t)(n0 + ty + p * 8) * K + k0 + tx] = f2bf(t[tx][ty + p * 8]);
}

// ---------------------------------------------------------------------------
// Kernel 4/5: MFMA GEMM  C = act(A[M,KDIM]bf16 @ Bt[N,KDIM]^T + bias)
// 64x64 tile (4 waves x 32x32), BK=128, global_load_lds width-16 staging,
// XOR chunk swizzle for conflict-free ds_read_b128.
// ---------------------------------------------------------------------------
template <int KDIM, bool RELU, bool OUTBF16>
__global__ __launch_bounds__(256) void gemm_mfma(
    const unsigned short* __restrict__ A,   // [M][KDIM] bf16
    const unsigned short* __restrict__ Bt,  // [N][KDIM] bf16
    const float* __restrict__ bias,
    void* __restrict__ Cout, int ldc) {
  __shared__ __align__(16) unsigned short Al[64 * 128];  // 16 KB
  __shared__ __align__(16) unsigned short Bl[64 * 128];  // 16 KB
  const int tid  = threadIdx.x;
  const int m0   = blockIdx.x * 64, n0 = blockIdx.y * 64;
  const int wv   = tid >> 6, lane = tid & 63;
  const int quad = lane >> 4, s = lane & 15;
  const int moff = (wv & 1) * 32, noff = (wv >> 1) * 32;
  const int lr   = lane >> 4;     // staging: row within 4-row group
  const int lc   = lane & 15;     // staging: 16B chunk within row

  floatx4 acc[2][2] = {{{0.f,0.f,0.f,0.f},{0.f,0.f,0.f,0.f}},
                       {{0.f,0.f,0.f,0.f},{0.f,0.f,0.f,0.f}}};

  for (int k0 = 0; k0 < KDIM; k0 += 128) {
#pragma unroll
    for (int t = 0; t < 4; ++t) {
      const int R0 = wv * 16 + t * 4;          // wave-uniform base row
      const int r  = R0 + lr;
      const int gc = lc ^ (r & 7);
      load_lds16(A  + (size_t)(m0 + r) * KDIM + k0 + gc * 8, &Al[R0 * 128]);
      load_lds16(Bt + (size_t)(n0 + r) * KDIM + k0 + gc * 8, &Bl[R0 * 128]);
    }
    __syncthreads();
#pragma unroll
    for (int h = 0; h < 4; ++h) {
      bf16x8 af[2], bfr[2];
#pragma unroll
      for (int i = 0; i < 2; ++i) {
        const int r = moff + i * 16 + s;
        af[i] = *reinterpret_cast<const bf16x8*>(
            &Al[(size_t)r * 128 + ((((h << 2) | quad) ^ (r & 7)) << 3)]);
      }
#pragma unroll
      for (int j = 0; j < 2; ++j) {
        const int r = noff + j * 16 + s;
        bfr[j] = *reinterpret_cast<const bf16x8*>(
            &Bl[(size_t)r * 128 + ((((h << 2) | quad) ^ (r & 7)) << 3)]);
      }
#pragma unroll
      for (int i = 0; i < 2; ++i)
#pragma unroll
        for (int j = 0; j < 2; ++j)
          acc[i][j] = __builtin_amdgcn_mfma_f32_16x16x32_bf16(af[i], bfr[j], acc[i][j], 0, 0, 0);
    }
    __syncthreads();
  }

#pragma unroll
  for (int i = 0; i < 2; ++i)
#pragma unroll
    for (int j = 0; j < 2; ++j) {
      const int col = n0 + noff + j * 16 + s;
      const float bv = bias[col];
#pragma unroll
      for (int r = 0; r < 4; ++r) {
        const int row = m0 + moff + i * 16 + quad * 4 + r;
        float v = acc[i][j][r] + bv;
        if (RELU) v = fmaxf(v, 0.f);
        if (OUTBF16)
          ((unsigned short*)Cout)[(size_t)row * ldc + col] = f2bf(v);
        else
          ((float*)Cout)[(size_t)row * ldc + col] = v;
      }
    }
}

// ---------------------------------------------------------------------------
extern "C" void kernel_launch(void* const* d_in, const int* in_sizes, int n_in,
                              void* d_out, int out_size, void* d_ws, size_t ws_size,
                              hipStream_t stream) {
  const float* keys   = (const float*)d_in[0];
  const float* points = (const float*)d_in[1];
  const float* feats  = (const float*)d_in[2];
  const float* wc0_W  = (const float*)d_in[3];
  const float* wc0_b  = (const float*)d_in[4];
  const float* wc1_W  = (const float*)d_in[5];
  const float* wc1_b  = (const float*)d_in[6];
  const float* wc2_W  = (const float*)d_in[7];
  const float* wc2_b  = (const float*)d_in[8];
  const float* fc0_W  = (const float*)d_in[9];
  const float* fc0_b  = (const float*)d_in[10];
  const float* fc1_W  = (const float*)d_in[11];
  const float* fc1_b  = (const float*)d_in[12];
  float* out = (float*)d_out;

  const int M = BATCH * KQ;   // 8192
  char* ws = (char*)d_ws;
  unsigned short* E    = (unsigned short*)(ws);                    // 32 MB
  unsigned short* H16  = (unsigned short*)(ws + (size_t)33554432); //  4 MB
  unsigned short* W0T  = (unsigned short*)(ws + (size_t)37748736); //  1 MB
  unsigned short* W1T  = (unsigned short*)(ws + (size_t)38797312); // 64 KB
  int*            nidx = (int*)(ws + (size_t)38862848);            // 512 KB

  select_topk<<<M, 256, 0, stream>>>(keys, points, nidx);
  transpose_bf16<<<dim3(64, 8), 256, 0, stream>>>(fc0_W, W0T, 2048, 256);
  transpose_bf16<<<dim3(8, 4), 256, 0, stream>>>(fc1_W, W1T, 256, 128);
  edge_mlp_e<<<M / QPB, 256, 0, stream>>>(keys, points, feats, nidx,
                                          wc0_W, wc0_b, wc1_W, wc1_b, wc2_W, wc2_b, E);
  gemm_mfma<2048, true,  true ><<<dim3(M / 64, 4), 256, 0, stream>>>(E, W0T, fc0_b, H16, 256);
  gemm_mfma<256,  false, false><<<dim3(M / 64, 2), 256, 0, stream>>>(H16, W1T, fc1_b, out, 128);
}

// Round 6
// 180.735 us; speedup vs baseline: 5.0309x; 1.0187x over previous
//
#include <hip/hip_runtime.h>
#include <cfloat>
#include <climits>

#define BATCH 4
#define KQ    2048
#define NP    4096
#define CIN   64
#define CMID  32
#define NB    16
#define NBINS 4096   // bits >> 19 : 8 exp bits + 4 mantissa bits
#define CANDCAP 256
#define QPB   8      // queries per block in edge_prep

typedef short   bf16x8  __attribute__((ext_vector_type(8)));
typedef float   floatx4 __attribute__((ext_vector_type(4)));

__device__ __forceinline__ unsigned short f2bf(float f) {
  unsigned u = __float_as_uint(f);
  u = (u + 0x7fffu + ((u >> 16) & 1u)) >> 16;   // RNE, inputs finite
  return (unsigned short)u;
}
__device__ __forceinline__ float bf2f(unsigned short u) {
  return __uint_as_float((unsigned)u << 16);
}

// async global->LDS, 16B per lane; LDS dst = base + lane*16 (wave-uniform base)
__device__ __forceinline__ void load_lds16(const void* g, void* l) {
  __builtin_amdgcn_global_load_lds(
      (const __attribute__((address_space(1))) unsigned int*)g,
      (__attribute__((address_space(3))) unsigned int*)l, 16, 0, 0);
}

// ---------------------------------------------------------------------------
// Kernel 1: radix-select top-16 per query -> nidx[8192][16] (set only; the
// einsum sums over n so order is irrelevant; boundary ties -> lower index).
// ---------------------------------------------------------------------------
__global__ __launch_bounds__(256) void select_topk(
    const float* __restrict__ keys, const float* __restrict__ points,
    int* __restrict__ nidx_g) {
  __shared__ int   hist[NBINS];            // 16 KB
  __shared__ int   psum[256];
  __shared__ float cand_d[CANDCAP];
  __shared__ int   cand_i[CANDCAP];
  __shared__ int   nidx[NB];
  __shared__ int   sel_cnt, cand_cnt, sBin, sCbelow;

  const int tid = threadIdx.x;
  const int b   = blockIdx.x >> 11;

  for (int i = tid; i < NBINS; i += 256) hist[i] = 0;
  if (tid == 0) { sel_cnt = 0; cand_cnt = 0; }

  const float kx = keys[blockIdx.x * 3 + 0];
  const float ky = keys[blockIdx.x * 3 + 1];
  const float kz = keys[blockIdx.x * 3 + 2];
  __syncthreads();

  // pass 1: thread owns 16 consecutive points (12 float4 loads), histograms
  const float4* pv =
      reinterpret_cast<const float4*>(points + (size_t)b * NP * 3) + (size_t)tid * 12;
  float f[48];
#pragma unroll
  for (int c = 0; c < 12; ++c) {
    const float4 v = pv[c];
    f[c * 4 + 0] = v.x; f[c * 4 + 1] = v.y; f[c * 4 + 2] = v.z; f[c * 4 + 3] = v.w;
  }
  float dreg[16];
#pragma unroll
  for (int j = 0; j < 16; ++j) {
    const float dx = f[j * 3 + 0] - kx;
    const float dy = f[j * 3 + 1] - ky;
    const float dz = f[j * 3 + 2] - kz;
    const float d  = dx * dx + dy * dy + dz * dz;
    dreg[j] = d;
    atomicAdd(&hist[__float_as_uint(d) >> 19], 1);
  }
  __syncthreads();

  // two-level threshold scan: per-thread 16-bin sums -> wave-0 shuffle scan
  {
    const int base = tid * 16;
    int s = 0;
#pragma unroll
    for (int j = 0; j < 16; ++j) s += hist[base + j];
    psum[tid] = s;
  }
  __syncthreads();

  if (tid < 64) {
    const int q = psum[tid * 4] + psum[tid * 4 + 1] + psum[tid * 4 + 2] + psum[tid * 4 + 3];
    int incl = q;
#pragma unroll
    for (int off = 1; off < 64; off <<= 1) {
      int u = __shfl_up(incl, off);
      if (tid >= off) incl += u;
    }
    unsigned long long bal = __ballot(incl >= NB);
    int firstlane = __ffsll((long long)bal) - 1;
    if (tid == firstlane) {
      int cum = incl - q;
      int bin = -1;
      for (int t = 0; t < 4 && bin < 0; ++t) {
        const int ps = psum[tid * 4 + t];
        if (cum + ps >= NB) {
          const int b0 = (tid * 4 + t) * 16;
          for (int j = 0; j < 16; ++j) {
            const int h = hist[b0 + j];
            if (cum + h >= NB) { bin = b0 + j; break; }
            cum += h;
          }
        } else cum += ps;
      }
      sBin = bin; sCbelow = cum;
    }
  }
  __syncthreads();

  const unsigned B = (unsigned)sBin;
#pragma unroll
  for (int j = 0; j < 16; ++j) {
    const int i = tid * 16 + j;
    const unsigned bk = __float_as_uint(dreg[j]) >> 19;
    if (bk < B) {
      int pos = atomicAdd(&sel_cnt, 1);
      nidx[pos] = i;
    } else if (bk == B) {
      int pos = atomicAdd(&cand_cnt, 1);
      if (pos < CANDCAP) { cand_d[pos] = dreg[j]; cand_i[pos] = i; }
    }
  }
  __syncthreads();

  if (tid < 64) {
    const int rem = NB - sCbelow;
    const int cc  = min(cand_cnt, CANDCAP);
    for (int s = 0; s < rem; ++s) {
      float bd = FLT_MAX; int bi = INT_MAX; int bp = -1;
      for (int j = tid; j < cc; j += 64) {
        float d = cand_d[j]; int ii = cand_i[j];
        if (d < bd || (d == bd && ii < bi)) { bd = d; bi = ii; bp = j; }
      }
#pragma unroll
      for (int off = 32; off > 0; off >>= 1) {
        float od = __shfl_down(bd, off);
        int   oi = __shfl_down(bi, off);
        int   op = __shfl_down(bp, off);
        if (od < bd || (od == bd && oi < bi)) { bd = od; bi = oi; bp = op; }
      }
      if (tid == 0) { nidx[sCbelow + s] = bi; cand_d[bp] = FLT_MAX; }
    }
  }
  __syncthreads();

  if (tid < NB) nidx_g[blockIdx.x * NB + tid] = nidx[tid];
}

// ---------------------------------------------------------------------------
// Kernel 2: edge MLP + aggregation -> E bf16, WITH both weight transposes
// folded in (blocks 0..511: W0 32x32 tiles; 512..543: W1 tiles) to cut two
// dispatches (~10 us launch overhead each). Transpose uses the u_mem union
// before the h2 phase claims it.
// ---------------------------------------------------------------------------
__global__ __launch_bounds__(256) void edge_prep(
    const float* __restrict__ keys, const float* __restrict__ points,
    const float* __restrict__ feats, const int* __restrict__ nidx_g,
    const float* __restrict__ wc0_W, const float* __restrict__ wc0_b,
    const float* __restrict__ wc1_W, const float* __restrict__ wc1_b,
    const float* __restrict__ wc2_W, const float* __restrict__ wc2_b,
    const float* __restrict__ fc0_W, const float* __restrict__ fc1_W,
    unsigned short* __restrict__ W0T, unsigned short* __restrict__ W1T,
    unsigned short* __restrict__ E) {
  __shared__ float w0[96], b0v[32], w1[1024], b1v[32], w2[1024], b2v[32];
  __shared__ int   idx_s[QPB * NB];                              // 512 B
  __shared__ __align__(16) unsigned short m_bf[QPB * NB][40];    // 10 KB
  __shared__ __align__(16) char u_mem[128 * 144];                // 18 KB union
  float (*h2_all)[33]        = reinterpret_cast<float(*)[33]>(u_mem);
  unsigned short (*f_bf)[72] = reinterpret_cast<unsigned short(*)[72]>(u_mem);
  float (*tt)[33]            = reinterpret_cast<float(*)[33]>(u_mem);

  const int tid = threadIdx.x;
  const int bid = blockIdx.x;
  const int q0  = bid * QPB;
  const int b   = q0 >> 11;

  // ---- folded weight transposes (f32 [K][N] -> bf16 [N][K]) ----
  if (bid < 544) {
    const float* W; unsigned short* WT; int K, N, k0, n0;
    if (bid < 512) { W = fc0_W; WT = W0T; K = 2048; N = 256;
                     k0 = (bid >> 3) * 32; n0 = (bid & 7) * 32; }
    else           { W = fc1_W; WT = W1T; K = 256;  N = 128;
                     k0 = ((bid - 512) >> 2) * 32; n0 = ((bid - 512) & 3) * 32; }
    const int tx = tid & 31, ty = tid >> 5;
#pragma unroll
    for (int p = 0; p < 4; ++p)
      tt[ty + p * 8][tx] = W[(size_t)(k0 + ty + p * 8) * N + n0 + tx];
    __syncthreads();
#pragma unroll
    for (int p = 0; p < 4; ++p)
      WT[(size_t)(n0 + ty + p * 8) * K + k0 + tx] = f2bf(tt[tx][ty + p * 8]);
    __syncthreads();   // u_mem free again
  }

  // ---- stage tiny MLP weights + neighbor indices ----
  if (tid < 96) w0[tid] = wc0_W[tid];
  for (int i = tid; i < 1024; i += 256) { w1[i] = wc1_W[i]; w2[i] = wc2_W[i]; }
  if (tid < 32) { b0v[tid] = wc0_b[tid]; b1v[tid] = wc1_b[tid]; b2v[tid] = wc2_b[tid]; }
  if (tid < QPB * NB) idx_s[tid] = nidx_g[q0 * NB + tid];
  __syncthreads();

  // ---- MLP: thread (edge, half) computes h1 fully, h2/m for 16 outputs ----
  const int edge = tid & 127;
  const int half = tid >> 7;
  const int ob   = half * 16;
  const int qe   = edge >> 4;
  const int idx  = idx_s[edge];
  {
    const float* p  = points + ((size_t)b * NP + idx) * 3;
    const float* kq = keys + (size_t)(q0 + qe) * 3;
    const float rx = p[0] - kq[0], ry = p[1] - kq[1], rz = p[2] - kq[2];

    float h1[32];
#pragma unroll
    for (int o = 0; o < 32; ++o)
      h1[o] = fmaxf(0.f, rx * w0[o] + ry * w0[32 + o] + rz * w0[64 + o] + b0v[o]);
#pragma unroll
    for (int j = 0; j < 16; ++j) {
      const int o = ob + j;
      float a = b1v[o];
#pragma unroll
      for (int i = 0; i < 32; ++i) a += h1[i] * w1[i * 32 + o];
      h2_all[edge][o] = fmaxf(a, 0.f);
    }
  }
  __syncthreads();

  float mo[16];
#pragma unroll
  for (int j = 0; j < 16; ++j) {
    const int o = ob + j;
    float a = b2v[o];
#pragma unroll
    for (int i = 0; i < 32; ++i) a += h2_all[edge][i] * w2[i * 32 + o];
    mo[j] = a;
  }
  // write m (bf16 pairs packed into dwords) — separate LDS region, pre-barrier
#pragma unroll
  for (int j = 0; j < 8; ++j) {
    const unsigned lo = f2bf(mo[2 * j]), hi = f2bf(mo[2 * j + 1]);
    *reinterpret_cast<unsigned*>(&m_bf[edge][ob + 2 * j]) = lo | (hi << 16);
  }
  __syncthreads();   // h2 region dead from here; f staging reuses u_mem

  // ---- stage neighbor features bf16: 128 rows x 16 float4-chunks ----
#pragma unroll
  for (int t = 0; t < 8; ++t) {
    const int task = tid + t * 256;          // 0..2047
    const int row = task >> 4, ch = task & 15;
    const float4 v = *reinterpret_cast<const float4*>(
        feats + ((size_t)b * NP + idx_s[row]) * CIN + ch * 4);
    ushort4 o4;
    o4.x = f2bf(v.x); o4.y = f2bf(v.y); o4.z = f2bf(v.z); o4.w = f2bf(v.w);
    *reinterpret_cast<ushort4*>(&f_bf[row][ch * 4]) = o4;
  }
  __syncthreads();

  // ---- e-comp: wave -> q, lane -> (mg: 4 mids, co: 8 ch), 2 q-iters ----
  const int wv = tid >> 6, lane = tid & 63;
  const int co = lane & 7, mg = lane >> 3;
#pragma unroll
  for (int it = 0; it < 2; ++it) {
    const int q = wv + it * 4;
    float acc[4][8] = {};
#pragma unroll
    for (int n = 0; n < 16; ++n) {
      const int row = q * 16 + n;
      const ushort4 m4 = *reinterpret_cast<const ushort4*>(&m_bf[row][mg * 4]);
      const float mv[4] = {bf2f(m4.x), bf2f(m4.y), bf2f(m4.z), bf2f(m4.w)};
      const uint4 fv = *reinterpret_cast<const uint4*>(&f_bf[row][co * 8]);
      float fc[8];
      fc[0] = __uint_as_float(fv.x << 16); fc[1] = __uint_as_float(fv.x & 0xffff0000u);
      fc[2] = __uint_as_float(fv.y << 16); fc[3] = __uint_as_float(fv.y & 0xffff0000u);
      fc[4] = __uint_as_float(fv.z << 16); fc[5] = __uint_as_float(fv.z & 0xffff0000u);
      fc[6] = __uint_as_float(fv.w << 16); fc[7] = __uint_as_float(fv.w & 0xffff0000u);
#pragma unroll
      for (int i = 0; i < 4; ++i)
#pragma unroll
        for (int j = 0; j < 8; ++j) acc[i][j] += mv[i] * fc[j];
    }
    unsigned short* Eq = E + (size_t)(q0 + q) * 2048;
#pragma unroll
    for (int i = 0; i < 4; ++i) {
      const int mid = mg * 4 + i;
      uint4 o;
      o.x = (unsigned)f2bf(acc[i][0]) | ((unsigned)f2bf(acc[i][1]) << 16);
      o.y = (unsigned)f2bf(acc[i][2]) | ((unsigned)f2bf(acc[i][3]) << 16);
      o.z = (unsigned)f2bf(acc[i][4]) | ((unsigned)f2bf(acc[i][5]) << 16);
      o.w = (unsigned)f2bf(acc[i][6]) | ((unsigned)f2bf(acc[i][7]) << 16);
      *reinterpret_cast<uint4*>(&Eq[mid * 64 + co * 8]) = o;
    }
  }
}

// ---------------------------------------------------------------------------
// Kernel 3/4: MFMA GEMM  C = act(A[M,KDIM]bf16 @ Bt[N,KDIM]^T + bias)
// 64x64 tile (4 waves x 32x32), BK=128, global_load_lds width-16 staging,
// XOR chunk swizzle for conflict-free ds_read_b128.
// ---------------------------------------------------------------------------
template <int KDIM, bool RELU, bool OUTBF16>
__global__ __launch_bounds__(256) void gemm_mfma(
    const unsigned short* __restrict__ A,   // [M][KDIM] bf16
    const unsigned short* __restrict__ Bt,  // [N][KDIM] bf16
    const float* __restrict__ bias,
    void* __restrict__ Cout, int ldc) {
  __shared__ __align__(16) unsigned short Al[64 * 128];  // 16 KB
  __shared__ __align__(16) unsigned short Bl[64 * 128];  // 16 KB
  const int tid  = threadIdx.x;
  const int m0   = blockIdx.x * 64, n0 = blockIdx.y * 64;
  const int wv   = tid >> 6, lane = tid & 63;
  const int quad = lane >> 4, s = lane & 15;
  const int moff = (wv & 1) * 32, noff = (wv >> 1) * 32;
  const int lr   = lane >> 4;     // staging: row within 4-row group
  const int lc   = lane & 15;     // staging: 16B chunk within row

  floatx4 acc[2][2] = {{{0.f,0.f,0.f,0.f},{0.f,0.f,0.f,0.f}},
                       {{0.f,0.f,0.f,0.f},{0.f,0.f,0.f,0.f}}};

  for (int k0 = 0; k0 < KDIM; k0 += 128) {
#pragma unroll
    for (int t = 0; t < 4; ++t) {
      const int R0 = wv * 16 + t * 4;          // wave-uniform base row
      const int r  = R0 + lr;
      const int gc = lc ^ (r & 7);
      load_lds16(A  + (size_t)(m0 + r) * KDIM + k0 + gc * 8, &Al[R0 * 128]);
      load_lds16(Bt + (size_t)(n0 + r) * KDIM + k0 + gc * 8, &Bl[R0 * 128]);
    }
    __syncthreads();
#pragma unroll
    for (int h = 0; h < 4; ++h) {
      bf16x8 af[2], bfr[2];
#pragma unroll
      for (int i = 0; i < 2; ++i) {
        const int r = moff + i * 16 + s;
        af[i] = *reinterpret_cast<const bf16x8*>(
            &Al[(size_t)r * 128 + ((((h << 2) | quad) ^ (r & 7)) << 3)]);
      }
#pragma unroll
      for (int j = 0; j < 2; ++j) {
        const int r = noff + j * 16 + s;
        bfr[j] = *reinterpret_cast<const bf16x8*>(
            &Bl[(size_t)r * 128 + ((((h << 2) | quad) ^ (r & 7)) << 3)]);
      }
#pragma unroll
      for (int i = 0; i < 2; ++i)
#pragma unroll
        for (int j = 0; j < 2; ++j)
          acc[i][j] = __builtin_amdgcn_mfma_f32_16x16x32_bf16(af[i], bfr[j], acc[i][j], 0, 0, 0);
    }
    __syncthreads();
  }

#pragma unroll
  for (int i = 0; i < 2; ++i)
#pragma unroll
    for (int j = 0; j < 2; ++j) {
      const int col = n0 + noff + j * 16 + s;
      const float bv = bias[col];
#pragma unroll
      for (int r = 0; r < 4; ++r) {
        const int row = m0 + moff + i * 16 + quad * 4 + r;
        float v = acc[i][j][r] + bv;
        if (RELU) v = fmaxf(v, 0.f);
        if (OUTBF16)
          ((unsigned short*)Cout)[(size_t)row * ldc + col] = f2bf(v);
        else
          ((float*)Cout)[(size_t)row * ldc + col] = v;
      }
    }
}

// ---------------------------------------------------------------------------
extern "C" void kernel_launch(void* const* d_in, const int* in_sizes, int n_in,
                              void* d_out, int out_size, void* d_ws, size_t ws_size,
                              hipStream_t stream) {
  const float* keys   = (const float*)d_in[0];
  const float* points = (const float*)d_in[1];
  const float* feats  = (const float*)d_in[2];
  const float* wc0_W  = (const float*)d_in[3];
  const float* wc0_b  = (const float*)d_in[4];
  const float* wc1_W  = (const float*)d_in[5];
  const float* wc1_b  = (const float*)d_in[6];
  const float* wc2_W  = (const float*)d_in[7];
  const float* wc2_b  = (const float*)d_in[8];
  const float* fc0_W  = (const float*)d_in[9];
  const float* fc0_b  = (const float*)d_in[10];
  const float* fc1_W  = (const float*)d_in[11];
  const float* fc1_b  = (const float*)d_in[12];
  float* out = (float*)d_out;

  const int M = BATCH * KQ;   // 8192
  char* ws = (char*)d_ws;
  unsigned short* E    = (unsigned short*)(ws);                    // 32 MB
  unsigned short* H16  = (unsigned short*)(ws + (size_t)33554432); //  4 MB
  unsigned short* W0T  = (unsigned short*)(ws + (size_t)37748736); //  1 MB
  unsigned short* W1T  = (unsigned short*)(ws + (size_t)38797312); // 64 KB
  int*            nidx = (int*)(ws + (size_t)38862848);            // 512 KB

  select_topk<<<M, 256, 0, stream>>>(keys, points, nidx);
  edge_prep<<<M / QPB, 256, 0, stream>>>(keys, points, feats, nidx,
                                         wc0_W, wc0_b, wc1_W, wc1_b, wc2_W, wc2_b,
                                         fc0_W, fc1_W, W0T, W1T, E);
  gemm_mfma<2048, true,  true ><<<dim3(M / 64, 4), 256, 0, stream>>>(E, W0T, fc0_b, H16, 256);
  gemm_mfma<256,  false, false><<<dim3(M / 64, 2), 256, 0, stream>>>(H16, W1T, fc1_b, out, 128);
}